// Round 19
// baseline (327.201 us; speedup 1.0000x reference)
//
#include <hip/hip_runtime.h>

#define LRELU 0.01f

// ---------------- problem constants ----------------
// relations: 0 follows U->U, 1 posts U->N, 2 posted_by N->U, 3 publishes S->N, 4 published_by N->S
static const int kNU = 50000, kNN = 20000, kNS = 2000;
static const int DOUT_OFF[5] = {0, 100000, 170000, 240000, 262000};
static const int DIN_OFF[5]  = {50000, 150000, 190000, 242000, 282000};
static const int RP_OFF[5]   = {0, 50001, 70002, 120003, 140004};
static const int CSR_OFF[5]  = {0, 500000, 800000, 1100000, 1250000};

using bf16x8 = __attribute__((ext_vector_type(8))) short;
using u16x8  = __attribute__((ext_vector_type(8))) unsigned short;
using f32x4  = __attribute__((ext_vector_type(4))) float;

__device__ __forceinline__ float bf2f(unsigned short u) {
  return __uint_as_float(((unsigned)u) << 16);
}
__device__ __forceinline__ unsigned short f2bf(float f) {  // RNE
  unsigned u = __float_as_uint(f);
  u += 0x7FFFu + ((u >> 16) & 1u);
  return (unsigned short)(u >> 16);
}

// ---------------- k_hist: LDS histograms (din rank + dout counts) ----------------

struct HArgs { const int* esrc[5]; const int* edst[5]; int* pos; int* partial; };

__global__ __launch_bounds__(512) void k_hist(HArgs a) {
  __shared__ int hbin[8192];
  int bx = blockIdx.x;
  int t = threadIdx.x;
  if (bx < 336) {
    constexpr int DSTART[6] = {0, 112, 160, 272, 320, 336};
    constexpr int NDT[5] = {50000, 20000, 50000, 20000, 2000};
    constexpr int CS[5]  = {31250, 18750, 18750, 9375, 9375};
    constexpr int EE[5]  = {500000, 300000, 300000, 150000, 150000};
    constexpr int PB[5]  = {0, 800000, 1120000, 1920000, 2240000};
    constexpr int COFF[5] = {0, 500000, 800000, 1100000, 1250000};
    int r = 0;
    while (bx >= DSTART[r + 1]) ++r;
    int local = bx - DSTART[r];
    int g = local / 16, c = local % 16;
    int nd = NDT[r];
    int gbase = g * 8192;
    int gend = gbase + 8192 < nd ? gbase + 8192 : nd;
    const int* dst = a.edst[r];
    int* pos = a.pos + COFF[r];
    int elo = c * CS[r];
    int ehi = elo + CS[r] < EE[r] ? elo + CS[r] : EE[r];
    for (int j = t; j < 8192; j += 512) hbin[j] = 0;
    __syncthreads();
    int span = ehi - elo;
    int efull = elo + (span / 4096) * 4096;
    for (int b = elo + t; b < efull; b += 4096) {
      int d[8];
#pragma unroll
      for (int k = 0; k < 8; ++k) d[k] = dst[b + k * 512];
#pragma unroll
      for (int k = 0; k < 8; ++k)
        if (d[k] >= gbase && d[k] < gend)
          pos[b + k * 512] = atomicAdd(&hbin[d[k] - gbase], 1);
    }
    for (int e = efull + t; e < ehi; e += 512) {
      int d = dst[e];
      if (d >= gbase && d < gend) pos[e] = atomicAdd(&hbin[d - gbase], 1);
    }
    __syncthreads();
    int* out = a.partial + PB[r] + (size_t)c * nd + gbase;
    int nn = gend - gbase;
    for (int j = t; j < nn; j += 512) out[j] = hbin[j];
  } else {
    constexpr int OSTART[6] = {0, 112, 224, 272, 288, 336};
    constexpr int NST[5] = {50000, 50000, 20000, 2000, 20000};
    constexpr int CS[5]  = {31250, 18750, 18750, 9375, 9375};
    constexpr int EE[5]  = {500000, 300000, 300000, 150000, 150000};
    constexpr int PB[5]  = {2272000, 3072000, 3872000, 4192000, 4224000};
    int idx = bx - 336;
    int r = 0;
    while (idx >= OSTART[r + 1]) ++r;
    int local = idx - OSTART[r];
    int g = local / 16, c = local % 16;
    int ns = NST[r];
    int gbase = g * 8192;
    int gend = gbase + 8192 < ns ? gbase + 8192 : ns;
    const int* src = a.esrc[r];
    int elo = c * CS[r];
    int ehi = elo + CS[r] < EE[r] ? elo + CS[r] : EE[r];
    for (int j = t; j < 8192; j += 512) hbin[j] = 0;
    __syncthreads();
    int span = ehi - elo;
    int efull = elo + (span / 4096) * 4096;
    for (int b = elo + t; b < efull; b += 4096) {
      int s[8];
#pragma unroll
      for (int k = 0; k < 8; ++k) s[k] = src[b + k * 512];
#pragma unroll
      for (int k = 0; k < 8; ++k)
        if (s[k] >= gbase && s[k] < gend) atomicAdd(&hbin[s[k] - gbase], 1);
    }
    for (int e = efull + t; e < ehi; e += 512) {
      int s = src[e];
      if (s >= gbase && s < gend) atomicAdd(&hbin[s - gbase], 1);
    }
    __syncthreads();
    int* out = a.partial + PB[r] + (size_t)c * ns + gbase;
    int nn = gend - gbase;
    for (int j = t; j < nn; j += 512) out[j] = hbin[j];
  }
}

// ---------------- phase B: chunk-prefix (din, in-place) + rs + cnt ----------------

struct BArgs { int* partial; int* cnt; float* rs; };

__global__ __launch_bounds__(256) void k_scanB(BArgs a) {
  int bx = blockIdx.x;
  int t = threadIdx.x;
  if (bx < 555) {
    int i = bx * 256 + t;
    if (i >= 142000) return;
    constexpr int NDT[5] = {50000, 20000, 50000, 20000, 2000};
    constexpr int PB[5]  = {0, 800000, 1120000, 1920000, 2240000};
    constexpr int DOFF[5] = {50000, 150000, 190000, 242000, 282000};
    int r, d;
    if      (i < 50000)  { r = 0; d = i; }
    else if (i < 70000)  { r = 1; d = i - 50000; }
    else if (i < 120000) { r = 2; d = i - 70000; }
    else if (i < 140000) { r = 3; d = i - 120000; }
    else                 { r = 4; d = i - 140000; }
    int nd = NDT[r];
    int* p = a.partial + PB[r] + d;
    int run = 0;
#pragma unroll
    for (int c = 0; c < 16; ++c) {
      int v = p[(size_t)c * nd];
      p[(size_t)c * nd] = run;
      run += v;
    }
    a.cnt[DOFF[r] + d] = run;
    a.rs[DOFF[r] + d] = rsqrtf((float)(run > 1 ? run : 1));
  } else {
    int i = (bx - 555) * 256 + t;
    if (i >= 142000) return;
    constexpr int NST[5] = {50000, 50000, 20000, 2000, 20000};
    constexpr int PB[5]  = {2272000, 3072000, 3872000, 4192000, 4224000};
    constexpr int OOFF[5] = {0, 100000, 170000, 240000, 262000};
    int r, s;
    if      (i < 50000)  { r = 0; s = i; }
    else if (i < 100000) { r = 1; s = i - 50000; }
    else if (i < 120000) { r = 2; s = i - 100000; }
    else if (i < 122000) { r = 3; s = i - 120000; }
    else                 { r = 4; s = i - 122000; }
    int ns = NST[r];
    const int* p = a.partial + PB[r] + s;
    int sum = 0;
#pragma unroll
    for (int c = 0; c < 16; ++c) sum += p[(size_t)c * ns];
    a.rs[OOFF[r] + s] = rsqrtf((float)(sum > 1 ? sum : 1));
  }
}

// ---------------- scan3: rp from cnt ----------------

struct S3Args { const int* cnt; int* rp; };

__global__ __launch_bounds__(256) void k_scan3(S3Args a) {
  constexpr int CSTART[6] = {0, 49, 69, 118, 138, 140};
  constexpr int NDT[5] = {50000, 20000, 50000, 20000, 2000};
  constexpr int DOFF[5] = {50000, 150000, 190000, 242000, 282000};
  constexpr int RPOFF[5] = {0, 50001, 70002, 120003, 140004};
  int bx = blockIdx.x, r = 0;
  while (bx >= CSTART[r + 1]) ++r;
  int chunk = bx - CSTART[r];
  int nch = CSTART[r + 1] - CSTART[r];
  int n = NDT[r];
  const int* cnt = a.cnt + DOFF[r];
  int* rp = a.rp + RPOFF[r];
  int t = threadIdx.x;
  __shared__ int sd[256];
  __shared__ int choff_sh;
  int lim = chunk * 1024;
  int pre = 0;
  for (int j = t; j < lim; j += 256) pre += cnt[j];
  sd[t] = pre;
  __syncthreads();
  for (int off = 128; off > 0; off >>= 1) {
    if (t < off) sd[t] += sd[t + off];
    __syncthreads();
  }
  if (t == 0) choff_sh = sd[0];
  __syncthreads();
  int idx0 = lim + t * 4;
  int v[4];
#pragma unroll
  for (int j = 0; j < 4; ++j) v[j] = (idx0 + j < n) ? cnt[idx0 + j] : 0;
  int tsum = v[0] + v[1] + v[2] + v[3];
  sd[t] = tsum;
  __syncthreads();
  for (int s = 1; s < 256; s <<= 1) {
    int add = (t >= s) ? sd[t - s] : 0;
    __syncthreads();
    sd[t] += add;
    __syncthreads();
  }
  int off = choff_sh + sd[t] - tsum;
#pragma unroll
  for (int j = 0; j < 4; ++j) {
    if (idx0 + j < n) rp[idx0 + j] = off;
    off += v[j];
  }
  if (chunk == nch - 1 && t == 255) rp[n] = choff_sh + sd[255];
}

// ---------------- k_buildCx: CSR scatter (x4) + transform(L1) + wprep, striped 1:2 ----------------

struct TJob { const float* X; const float* W; unsigned short* Y; int M; };
struct PrepJob { const float* W0; const float* W128; unsigned short* hi;
                 unsigned short* lo; int NOUT; int lgK; int bstart; };
struct CXArgs { const int* esrc[5]; const int* edst[5]; const int* pos;
                const int* rp; const int* partial; int* csr;
                TJob tj[5]; PrepJob pj[6]; };

__device__ __forceinline__ void transform_body(const TJob& p, int bxl, int t) {
  int w = t >> 6, l = t & 63;
  int lo16 = l & 15, hi4 = l >> 4;
  int m0 = bxl * 64;
  int M = p.M;
  f32x4 acc[4][2] = {};
  for (int s = 0; s < 4; ++s) {  // K = 128, 32 per step
    int kbase = s * 32 + hi4 * 8;
    bf16x8 af[4];
#pragma unroll
    for (int mf = 0; mf < 4; ++mf) {
      int row = m0 + mf * 16 + lo16;
      row = row < M ? row : M - 1;  // clamp; OOB rows never stored
      const float* xr = &p.X[(size_t)row * 128 + kbase];
      float4 xa = *(const float4*)xr;
      float4 xb = *(const float4*)(xr + 4);
      af[mf][0] = (short)f2bf(xa.x); af[mf][1] = (short)f2bf(xa.y);
      af[mf][2] = (short)f2bf(xa.z); af[mf][3] = (short)f2bf(xa.w);
      af[mf][4] = (short)f2bf(xb.x); af[mf][5] = (short)f2bf(xb.y);
      af[mf][6] = (short)f2bf(xb.z); af[mf][7] = (short)f2bf(xb.w);
    }
#pragma unroll
    for (int nf = 0; nf < 2; ++nf) {
      int n = (w * 2 + nf) * 16 + lo16;
      bf16x8 bh, bl;
#pragma unroll
      for (int j = 0; j < 8; ++j) {
        float wv = p.W[(size_t)(kbase + j) * 128 + n];
        unsigned short h = f2bf(wv);
        bh[j] = (short)h;
        bl[j] = (short)f2bf(wv - bf2f(h));
      }
#pragma unroll
      for (int mf = 0; mf < 4; ++mf) {
        acc[mf][nf] = __builtin_amdgcn_mfma_f32_16x16x32_bf16(af[mf], bh, acc[mf][nf], 0, 0, 0);
        acc[mf][nf] = __builtin_amdgcn_mfma_f32_16x16x32_bf16(af[mf], bl, acc[mf][nf], 0, 0, 0);
      }
    }
  }
#pragma unroll
  for (int nf = 0; nf < 2; ++nf) {
    int col = (w * 2 + nf) * 16 + lo16;
#pragma unroll
    for (int mf = 0; mf < 4; ++mf) {
#pragma unroll
      for (int rr = 0; rr < 4; ++rr) {
        int row = m0 + mf * 16 + hi4 * 4 + rr;
        if (row < M) p.Y[(size_t)row * 128 + col] = f2bf(acc[mf][nf][rr]);
      }
    }
  }
}

__global__ __launch_bounds__(256) void k_buildCx(CXArgs a) {
  int bx = blockIdx.x;
  int t = threadIdx.x;
  int g = bx / 3, m = bx % 3;
  if (m == 0) {
    // CSR scatter, 1024 edges/block, 4/thread unrolled
    constexpr int ESTART[6] = {0, 489, 782, 1075, 1222, 1369};
    constexpr int NDT[5] = {50000, 20000, 50000, 20000, 2000};
    constexpr int CS[5]  = {31250, 18750, 18750, 9375, 9375};
    constexpr int EE[5]  = {500000, 300000, 300000, 150000, 150000};
    constexpr int PB[5]  = {0, 800000, 1120000, 1920000, 2240000};
    constexpr int RPOFF[5] = {0, 50001, 70002, 120003, 140004};
    constexpr int COFF[5] = {0, 500000, 800000, 1100000, 1250000};
    int idx = g;
    if (idx >= 1369) return;
    int r = 0;
    while (idx >= ESTART[r + 1]) ++r;
    int i0 = (idx - ESTART[r]) * 1024 + t;
    const int* edst = a.edst[r];
    const int* esrc = a.esrc[r];
    const int* pos = a.pos + COFF[r];
    const int* rp = a.rp + RPOFF[r];
    const int* pb = a.partial + PB[r];
    int* csr = a.csr + COFF[r];
    int E = EE[r], cs = CS[r], nd = NDT[r];
    int i[4], d[4];
    bool v[4];
#pragma unroll
    for (int k = 0; k < 4; ++k) {
      i[k] = i0 + k * 256;
      v[k] = i[k] < E;
      d[k] = v[k] ? edst[i[k]] : 0;
    }
    int slot[4];
#pragma unroll
    for (int k = 0; k < 4; ++k) {
      if (v[k]) {
        int c = i[k] / cs;
        slot[k] = rp[d[k]] + pb[(size_t)c * nd + d[k]] + pos[i[k]];
      }
    }
#pragma unroll
    for (int k = 0; k < 4; ++k)
      if (v[k]) csr[slot[k]] = esrc[i[k]];
  } else {
    int idx = g * 2 + (m - 1);
    if (idx < 2222) {
      constexpr int TSTART[6] = {0, 782, 1564, 1877, 1909, 2222};
      int r = 0;
      while (idx >= TSTART[r + 1]) ++r;
      transform_body(a.tj[r], idx - TSTART[r], t);
    } else if (idx < 2638) {
      int b = idx - 2222, ji = 0;
      while (ji < 5 && b >= a.pj[ji + 1].bstart) ++ji;
      PrepJob p = a.pj[ji];
      int eidx = (b - p.bstart) * 256 + t;
      int K = 1 << p.lgK;
      int n = eidx >> p.lgK, k = eidx & (K - 1);
      if (n >= p.NOUT) return;
      float w = (k < 128) ? p.W0[k * p.NOUT + n] : p.W128[(k - 128) * p.NOUT + n];
      unsigned short h = f2bf(w);
      float res = w - bf2f(h);
      p.hi[n * K + k] = h;
      p.lo[n * K + k] = f2bf(res);
    }
  }
}

// ---------------- shared gather inner loop ----------------

#define GROW(vv, cc)                                                              \
  _Pragma("unroll") for (int q = 0; q < 8; ++q)                                   \
      acc[q] = fmaf(__uint_as_float(((unsigned)(unsigned short)vv[q]) << 16), cc, acc[q]);

__device__ __forceinline__ void gat_accum(const int* __restrict__ rp,
    const int* __restrict__ csr, const unsigned short* __restrict__ Y,
    const float* __restrict__ rso, int wid, int sub, float* acc) {
  int e0 = rp[wid], e1 = rp[wid + 1];
  for (int base = e0; base < e1; base += 16) {
    int m = e1 - base;
    if (m > 16) m = 16;
    int ei = base + (sub < m ? sub : 0);
    int se = csr[ei];
    float sc = rso[se];
    if (m == 16) {
      bf16x8 v[16];
#pragma unroll
      for (int j = 0; j < 16; ++j) {
        int sj = __shfl(se, j, 16);
        v[j] = *(const bf16x8*)&Y[(size_t)sj * 128 + sub * 8];
      }
#pragma unroll
      for (int j = 0; j < 16; ++j) {
        float cj = __shfl(sc, j, 16);
        GROW(v[j], cj)
      }
    } else {
      int j = 0;
      for (; j + 8 <= m; j += 8) {
        int s0 = __shfl(se, j, 16), s1 = __shfl(se, j + 1, 16);
        int s2 = __shfl(se, j + 2, 16), s3 = __shfl(se, j + 3, 16);
        int s4 = __shfl(se, j + 4, 16), s5 = __shfl(se, j + 5, 16);
        int s6 = __shfl(se, j + 6, 16), s7 = __shfl(se, j + 7, 16);
        float c0 = __shfl(sc, j, 16), c1 = __shfl(sc, j + 1, 16);
        float c2 = __shfl(sc, j + 2, 16), c3 = __shfl(sc, j + 3, 16);
        float c4 = __shfl(sc, j + 4, 16), c5 = __shfl(sc, j + 5, 16);
        float c6 = __shfl(sc, j + 6, 16), c7 = __shfl(sc, j + 7, 16);
        bf16x8 v0 = *(const bf16x8*)&Y[(size_t)s0 * 128 + sub * 8];
        bf16x8 v1 = *(const bf16x8*)&Y[(size_t)s1 * 128 + sub * 8];
        bf16x8 v2 = *(const bf16x8*)&Y[(size_t)s2 * 128 + sub * 8];
        bf16x8 v3 = *(const bf16x8*)&Y[(size_t)s3 * 128 + sub * 8];
        bf16x8 v4 = *(const bf16x8*)&Y[(size_t)s4 * 128 + sub * 8];
        bf16x8 v5 = *(const bf16x8*)&Y[(size_t)s5 * 128 + sub * 8];
        bf16x8 v6 = *(const bf16x8*)&Y[(size_t)s6 * 128 + sub * 8];
        bf16x8 v7 = *(const bf16x8*)&Y[(size_t)s7 * 128 + sub * 8];
        GROW(v0, c0) GROW(v1, c1) GROW(v2, c2) GROW(v3, c3)
        GROW(v4, c4) GROW(v5, c5) GROW(v6, c6) GROW(v7, c7)
      }
      for (; j < m; ++j) {
        int s0 = __shfl(se, j, 16);
        float c0 = __shfl(sc, j, 16);
        bf16x8 v0 = *(const bf16x8*)&Y[(size_t)s0 * 128 + sub * 8];
        GROW(v0, c0)
      }
    }
  }
}

// ---------------- layer-1 gather: Y -> h1 bf16 (bias + mean + lrelu fused) ----------------

struct G1Rel { const int* rp; const int* csr; const unsigned short* Y;
               const float* rso; const float* rsi; };
struct G1Args { G1Rel rel[5]; const float* b;
                unsigned short* hU; unsigned short* hN; unsigned short* hS; };

__global__ __launch_bounds__(256) void k_gather1(G1Args a) {
  int bx = blockIdx.x;
  int t = threadIdx.x;
  int sub = t & 15;
  float acc[8], tot[8];
#pragma unroll
  for (int q = 0; q < 8; ++q) acc[q] = 0.f;
  if (bx < 3125) {  // users: rel 0 + rel 2
    int wid = bx * 16 + (t >> 4);
    gat_accum(a.rel[0].rp, a.rel[0].csr, a.rel[0].Y, a.rel[0].rso, wid, sub, acc);
    float s0 = a.rel[0].rsi[wid];
#pragma unroll
    for (int q = 0; q < 8; ++q) { tot[q] = s0 * acc[q]; acc[q] = 0.f; }
    gat_accum(a.rel[2].rp, a.rel[2].csr, a.rel[2].Y, a.rel[2].rso, wid, sub, acc);
    float s2 = a.rel[2].rsi[wid];
    const float* b0 = a.b;
    const float* b2 = a.b + 2 * 128;
    u16x8 o;
#pragma unroll
    for (int q = 0; q < 8; ++q) {
      float v = 0.5f * (tot[q] + s2 * acc[q] + b0[sub * 8 + q] + b2[sub * 8 + q]);
      v = v >= 0.f ? v : LRELU * v;
      o[q] = f2bf(v);
    }
    *(u16x8*)&a.hU[(size_t)wid * 128 + sub * 8] = o;
  } else if (bx < 4375) {  // news: rel 1 + rel 3
    int wid = (bx - 3125) * 16 + (t >> 4);
    gat_accum(a.rel[1].rp, a.rel[1].csr, a.rel[1].Y, a.rel[1].rso, wid, sub, acc);
    float s1 = a.rel[1].rsi[wid];
#pragma unroll
    for (int q = 0; q < 8; ++q) { tot[q] = s1 * acc[q]; acc[q] = 0.f; }
    gat_accum(a.rel[3].rp, a.rel[3].csr, a.rel[3].Y, a.rel[3].rso, wid, sub, acc);
    float s3 = a.rel[3].rsi[wid];
    const float* b1v = a.b + 128;
    const float* b3 = a.b + 3 * 128;
    u16x8 o;
#pragma unroll
    for (int q = 0; q < 8; ++q) {
      float v = 0.5f * (tot[q] + s3 * acc[q] + b1v[sub * 8 + q] + b3[sub * 8 + q]);
      v = v >= 0.f ? v : LRELU * v;
      o[q] = f2bf(v);
    }
    *(u16x8*)&a.hN[(size_t)wid * 128 + sub * 8] = o;
  } else {  // sources: rel 4
    int wid = (bx - 4375) * 16 + (t >> 4);
    gat_accum(a.rel[4].rp, a.rel[4].csr, a.rel[4].Y, a.rel[4].rso, wid, sub, acc);
    float s4 = a.rel[4].rsi[wid];
    const float* b4 = a.b + 4 * 128;
    u16x8 o;
#pragma unroll
    for (int q = 0; q < 8; ++q) {
      float v = s4 * acc[q] + b4[sub * 8 + q];
      v = v >= 0.f ? v : LRELU * v;
      o[q] = f2bf(v);
    }
    *(u16x8*)&a.hS[(size_t)wid * 128 + sub * 8] = o;
  }
}

// ---------------- k_gmm: fused layer-2 gather (swizzled LDS) + MFMA GEMM ----------------
// 256 threads, 32 rows/block (16KB LDS): 8 blocks/CU co-resident, half the
// barrier-tail imbalance of the 64-row tile. 4 waves each compute
// 32 rows x 32 cols. h2 f32 -> d_out, h2 bf16 -> h2b (not xb*: other blocks
// still read xb* as h1).

struct GMJob {
  const int* rpA; const int* csrA; const unsigned short* YA;
  const float* rsoA; const float* rsiA;
  const int* rpB; const int* csrB; const unsigned short* YB;
  const float* rsoB; const float* rsiB;
  const unsigned short* Wh; const unsigned short* Wl;
  const float* b0; const float* b1; float scale;
  float* H; unsigned short* Hb; int M; int KP;
};
struct GMArgs { GMJob j[3]; };

__global__ __launch_bounds__(256) void k_gmm(GMArgs a) {
  __shared__ unsigned short As[32 * 256];
  int bx = blockIdx.x;
  int ji, bxl;
  if (bx < 1563)      { ji = 0; bxl = bx; }
  else if (bx < 2188) { ji = 1; bxl = bx - 1563; }
  else                { ji = 2; bxl = bx - 2188; }
  const GMJob& p = a.j[ji];
  int t = threadIdx.x;
  int m0 = bxl * 32;
  char* asb = (char*)As;
  // ---- gather phase: 16 rows per pass (256/16), 2 passes ----
  int sub = t & 15;
  int rowloc = t >> 4;  // 0..15
  for (int half = 0; half < 2; ++half) {
    int rl = rowloc + half * 16;
    int wid = m0 + rl;
    bool ok = wid < p.M;
    {
      float acc[8];
#pragma unroll
      for (int q = 0; q < 8; ++q) acc[q] = 0.f;
      float si = 0.f;
      if (ok) { gat_accum(p.rpA, p.csrA, p.YA, p.rsoA, wid, sub, acc); si = p.rsiA[wid]; }
      u16x8 o;
#pragma unroll
      for (int q = 0; q < 8; ++q) o[q] = f2bf(acc[q] * si);
      int cb = sub * 16;
      *(u16x8*)(asb + rl * 512 + (cb ^ ((rl & 7) << 4))) = o;
    }
    if (p.rpB) {
      float acc[8];
#pragma unroll
      for (int q = 0; q < 8; ++q) acc[q] = 0.f;
      float si = 0.f;
      if (ok) { gat_accum(p.rpB, p.csrB, p.YB, p.rsoB, wid, sub, acc); si = p.rsiB[wid]; }
      u16x8 o;
#pragma unroll
      for (int q = 0; q < 8; ++q) o[q] = f2bf(acc[q] * si);
      int cb = 256 + sub * 16;
      *(u16x8*)(asb + rl * 512 + (cb ^ ((rl & 7) << 4))) = o;
    }
  }
  __syncthreads();
  // ---- GEMM phase: 4 waves, each 32 rows x 32 cols ----
  int w = t >> 6, l = t & 63;
  int lo16 = l & 15, hi4 = l >> 4;
  int KP = p.KP;
  f32x4 acc[2][2] = {};
  for (int s = 0; s < KP / 32; ++s) {
    int kbase = s * 32 + hi4 * 8;
    int cb = kbase * 2;
    bf16x8 af[2];
#pragma unroll
    for (int mf = 0; mf < 2; ++mf) {
      int row = mf * 16 + lo16;
      af[mf] = *(const bf16x8*)(asb + row * 512 + (cb ^ ((row & 7) << 4)));
    }
#pragma unroll
    for (int nf = 0; nf < 2; ++nf) {
      int n = w * 32 + nf * 16 + lo16;
      bf16x8 bh = *(const bf16x8*)&p.Wh[(size_t)n * KP + kbase];
      bf16x8 bl = *(const bf16x8*)&p.Wl[(size_t)n * KP + kbase];
#pragma unroll
      for (int mf = 0; mf < 2; ++mf) {
        acc[mf][nf] = __builtin_amdgcn_mfma_f32_16x16x32_bf16(af[mf], bh, acc[mf][nf], 0, 0, 0);
        acc[mf][nf] = __builtin_amdgcn_mfma_f32_16x16x32_bf16(af[mf], bl, acc[mf][nf], 0, 0, 0);
      }
    }
  }
#pragma unroll
  for (int nf = 0; nf < 2; ++nf) {
    int col = w * 32 + nf * 16 + lo16;
    float bs = p.b0[col];
    if (p.b1) bs += p.b1[col];
#pragma unroll
    for (int mf = 0; mf < 2; ++mf) {
#pragma unroll
      for (int rr = 0; rr < 4; ++rr) {
        int row = m0 + mf * 16 + hi4 * 4 + rr;
        if (row < p.M) {
          float o = p.scale * (acc[mf][nf][rr] + bs);
          o = o >= 0.f ? o : LRELU * o;
          p.H[(size_t)row * 128 + col] = o;
          p.Hb[(size_t)row * 128 + col] = f2bf(o);
        }
      }
    }
  }
}

// ---------------- projection GEMM (3 dst-types, one launch) ----------------

struct MJob { const unsigned short* A; const unsigned short* Wh; const unsigned short* Wl;
              const float* b0; const float* b1; float scale; int lrelu;
              float* H; int ldh; unsigned short* Hb; int M; int bstart; };
struct MArgs { MJob j[3]; };

template <int KCH, int NW>
__device__ __forceinline__ void mgemm_body(const MJob& p, int bxl) {
  constexpr int KP = KCH * 128;
  int t = threadIdx.x;
  int w = t >> 6, l = t & 63;
  int lo16 = l & 15, hi4 = l >> 4;
  int m0 = bxl * 64;
  int M = p.M;
  const unsigned short* A = p.A;
  f32x4 acc[4][NW] = {};
  for (int s = 0; s < KP / 32; ++s) {
    int kbase = s * 32 + hi4 * 8;
    bf16x8 af[4];
#pragma unroll
    for (int mf = 0; mf < 4; ++mf) {
      int row = m0 + mf * 16 + lo16;
      row = row < M ? row : M - 1;  // clamp; OOB rows never stored
      af[mf] = *(const bf16x8*)&A[(size_t)row * KP + kbase];
    }
#pragma unroll
    for (int nf = 0; nf < NW; ++nf) {
      int n = (w * NW + nf) * 16 + lo16;
      bf16x8 bh = *(const bf16x8*)&p.Wh[(size_t)n * KP + kbase];
      bf16x8 bl = *(const bf16x8*)&p.Wl[(size_t)n * KP + kbase];
#pragma unroll
      for (int mf = 0; mf < 4; ++mf) {
        acc[mf][nf] = __builtin_amdgcn_mfma_f32_16x16x32_bf16(af[mf], bh, acc[mf][nf], 0, 0, 0);
        acc[mf][nf] = __builtin_amdgcn_mfma_f32_16x16x32_bf16(af[mf], bl, acc[mf][nf], 0, 0, 0);
      }
    }
  }
#pragma unroll
  for (int nf = 0; nf < NW; ++nf) {
    int col = (w * NW + nf) * 16 + lo16;
    float bs = p.b0 ? p.b0[col] : 0.f;
    if (p.b1) bs += p.b1[col];
#pragma unroll
    for (int mf = 0; mf < 4; ++mf) {
#pragma unroll
      for (int rr = 0; rr < 4; ++rr) {
        int row = m0 + mf * 16 + hi4 * 4 + rr;
        if (row < M) {
          float o = p.scale * (acc[mf][nf][rr] + bs);
          if (p.lrelu) o = o >= 0.f ? o : LRELU * o;
          if (p.H) p.H[(size_t)row * p.ldh + col] = o;
          if (p.Hb) p.Hb[(size_t)row * p.ldh + col] = f2bf(o);
        }
      }
    }
  }
}

__global__ __launch_bounds__(256) void k_proj3(MArgs a) {
  int bx = blockIdx.x;
  if (bx < a.j[1].bstart)      mgemm_body<1, 1>(a.j[0], bx);
  else if (bx < a.j[2].bstart) mgemm_body<1, 1>(a.j[1], bx - a.j[1].bstart);
  else                         mgemm_body<1, 1>(a.j[2], bx - a.j[2].bstart);
}

// ---------------- host ----------------

extern "C" void kernel_launch(void* const* d_in, const int* in_sizes, int n_in,
                              void* d_out, int out_size, void* d_ws, size_t ws_size,
                              hipStream_t stream) {
  const float* xu = (const float*)d_in[0];
  const float* xn = (const float*)d_in[1];
  const float* xs = (const float*)d_in[2];
  const float* W1 = (const float*)d_in[3];
  const float* b1 = (const float*)d_in[4];
  const float* W2 = (const float*)d_in[5];
  const float* b2 = (const float*)d_in[6];
  const float* Wu = (const float*)d_in[7];
  const float* bu = (const float*)d_in[8];
  const float* Wn = (const float*)d_in[9];
  const float* bn = (const float*)d_in[10];
  const float* Wsrc = (const float*)d_in[11];
  const float* bsrc = (const float*)d_in[12];
  const int* SRC[5] = {(const int*)d_in[13], (const int*)d_in[15], (const int*)d_in[17],
                       (const int*)d_in[19], (const int*)d_in[21]};
  const int* DST[5] = {(const int*)d_in[14], (const int*)d_in[16], (const int*)d_in[18],
                       (const int*)d_in[20], (const int*)d_in[22]};

  // ---- workspace layout ----
  int* ws_i = (int*)d_ws;
  int* rp = ws_i;                           // 142008
  int* csr = ws_i + 142008;                 // 1400000
  int* pos = ws_i + 1542008;                // 1400000
  int* cnt = ws_i + 2942328;                // 284000 (din slots used)
  float* rs = (float*)(ws_i + 3226328);     // 284000
  unsigned short* wt = (unsigned short*)(rs + 284000);    // 376832
  unsigned short* h2bU = wt + 376832;       // 50000*128 (h2 bf16)
  unsigned short* h2bN = h2bU + 6400000;    // 20000*128
  unsigned short* h2bS = h2bN + 2560000;    // 2000*128
  unsigned short* xbU = wt + 376832 + 18176000; // 50000*128 (h1 bf16)
  unsigned short* xbN = xbU + 6400000;      // 20000*128
  unsigned short* xbS = xbN + 2560000;      // 2000*128

  // wt sub-offsets (hi, lo consecutive)
  unsigned short* L2U_h = wt + 163840, * L2U_l = wt + 196608;
  unsigned short* L2N_h = wt + 229376, * L2N_l = wt + 262144;
  unsigned short* L2S_h = wt + 294912, * L2S_l = wt + 311296;
  unsigned short* PU_h = wt + 327680, * PU_l = wt + 335872;
  unsigned short* PN_h = wt + 344064, * PN_l = wt + 352256;
  unsigned short* PS_h = wt + 360448, * PS_l = wt + 368640;

  // ---- d_out layout ----
  float* outf = (float*)d_out;
  float* ou = outf;                 // 50000*64
  float* on = outf + 3200000;       // 20000*64
  float* osrc = outf + 4480000;     // 2000*64
  float* hu = outf + 4608000;       // 50000*128
  float* hn = outf + 11008000;      // 20000*128
  float* hs = outf + 13568000;      // 2000*128

  // histogram partials / chunk-bases: 4.544M ints in ou+on+osrc region,
  // dead until k_proj3; consumed by scanB/scan3/buildCx.
  int* partial = (int*)outf;

  // layer-1 transform outputs Y_r (bf16) in hu/hn/hs region; consumed by
  // k_gather1, dead before k_gmm overwrites hu/hn/hs with h2 f32.
  unsigned short* Yb = (unsigned short*)(outf + 4608000);
  unsigned short* Y0 = Yb;              // 50000*128 (follows, src U)
  unsigned short* Y1 = Y0 + 6400000;    // 50000*128 (posts, src U)
  unsigned short* Y2a = Y1 + 6400000;   // 20000*128 (posted_by, src N)
  unsigned short* Y3 = Y2a + 2560000;   // 2000*128  (publishes, src S)
  unsigned short* Y4 = Y3 + 256000;     // 20000*128 (published_by, src N)

  // ---- k_hist: din rank-hist + dout hist (512t, unroll-8) ----
  HArgs ha;
  for (int r = 0; r < 5; ++r) { ha.esrc[r] = SRC[r]; ha.edst[r] = DST[r]; }
  ha.pos = pos;
  ha.partial = partial;
  k_hist<<<672, 512, 0, stream>>>(ha);

  // ---- phase B: chunk prefixes + rs + cnt ----
  BArgs ba = {partial, cnt, rs};
  k_scanB<<<1110, 256, 0, stream>>>(ba);

  // ---- rp scan ----
  S3Args s3 = {cnt, rp};
  k_scan3<<<140, 256, 0, stream>>>(s3);

  // ---- buildC (x4 unrolled) + transform(L1) + wprep, striped 1:2 ----
  CXArgs ca;
  for (int r = 0; r < 5; ++r) { ca.esrc[r] = SRC[r]; ca.edst[r] = DST[r]; }
  ca.pos = pos;
  ca.rp = rp;
  ca.partial = partial;
  ca.csr = csr;
  ca.tj[0] = {xu, W1 + 0 * 16384, Y0, kNU};
  ca.tj[1] = {xu, W1 + 1 * 16384, Y1, kNU};
  ca.tj[2] = {xn, W1 + 2 * 16384, Y2a, kNN};
  ca.tj[3] = {xs, W1 + 3 * 16384, Y3, kNS};
  ca.tj[4] = {xn, W1 + 4 * 16384, Y4, kNN};
  ca.pj[0] = {W2, W2 + 2 * 16384, L2U_h, L2U_l, 128, 8, 0};
  ca.pj[1] = {W2 + 16384, W2 + 3 * 16384, L2N_h, L2N_l, 128, 8, 128};
  ca.pj[2] = {W2 + 4 * 16384, nullptr, L2S_h, L2S_l, 128, 7, 256};
  ca.pj[3] = {Wu, nullptr, PU_h, PU_l, 64, 7, 320};
  ca.pj[4] = {Wn, nullptr, PN_h, PN_l, 64, 7, 352};
  ca.pj[5] = {Wsrc, nullptr, PS_h, PS_l, 64, 7, 384};
  k_buildCx<<<4107, 256, 0, stream>>>(ca);

  // ---- layer 1: gather Y -> h1 (bf16 into xb*) ----
  G1Args g1;
  const unsigned short* YT[5] = {Y0, Y1, Y2a, Y3, Y4};
  for (int r = 0; r < 5; ++r)
    g1.rel[r] = {rp + RP_OFF[r], csr + CSR_OFF[r], YT[r],
                 rs + DOUT_OFF[r], rs + DIN_OFF[r]};
  g1.b = b1;
  g1.hU = xbU; g1.hN = xbN; g1.hS = xbS;
  k_gather1<<<4500, 256, 0, stream>>>(g1);

  // ---- layer 2: fused gather+GEMM -> h2 (f32 into d_out, bf16 into h2b*) ----
  GMArgs gm;
  gm.j[0] = {rp + RP_OFF[0], csr + CSR_OFF[0], xbU, rs + DOUT_OFF[0], rs + DIN_OFF[0],
             rp + RP_OFF[2], csr + CSR_OFF[2], xbN, rs + DOUT_OFF[2], rs + DIN_OFF[2],
             L2U_h, L2U_l, b2, b2 + 2 * 128, 0.5f, hu, h2bU, kNU, 256};
  gm.j[1] = {rp + RP_OFF[1], csr + CSR_OFF[1], xbU, rs + DOUT_OFF[1], rs + DIN_OFF[1],
             rp + RP_OFF[3], csr + CSR_OFF[3], xbS, rs + DOUT_OFF[3], rs + DIN_OFF[3],
             L2N_h, L2N_l, b2 + 128, b2 + 3 * 128, 0.5f, hn, h2bN, kNN, 256};
  gm.j[2] = {rp + RP_OFF[4], csr + CSR_OFF[4], xbN, rs + DOUT_OFF[4], rs + DIN_OFF[4],
             nullptr, nullptr, nullptr, nullptr, nullptr,
             L2S_h, L2S_l, b2 + 4 * 128, nullptr, 1.0f, hs, h2bS, kNS, 128};
  k_gmm<<<2251, 256, 0, stream>>>(gm);

  // ---- output projections (read bf16 h2 from h2b*) ----
  MArgs pm;
  pm.j[0] = {h2bU, PU_h, PU_l, bu, nullptr, 1.0f, 0, ou, 64, nullptr, kNU, 0};
  pm.j[1] = {h2bN, PN_h, PN_l, bn, nullptr, 1.0f, 0, on, 64, nullptr, kNN, 782};
  pm.j[2] = {h2bS, PS_h, PS_l, bsrc, nullptr, 1.0f, 0, osrc, 64, nullptr, kNS, 1095};
  k_proj3<<<1127, 256, 0, stream>>>(pm);
}

// Round 20
// 306.970 us; speedup vs baseline: 1.0659x; 1.0659x over previous
//
#include <hip/hip_runtime.h>

#define LRELU 0.01f

// ---------------- problem constants ----------------
// relations: 0 follows U->U, 1 posts U->N, 2 posted_by N->U, 3 publishes S->N, 4 published_by N->S
static const int kNU = 50000, kNN = 20000, kNS = 2000;
static const int DOUT_OFF[5] = {0, 100000, 170000, 240000, 262000};
static const int DIN_OFF[5]  = {50000, 150000, 190000, 242000, 282000};
static const int RP_OFF[5]   = {0, 50001, 70002, 120003, 140004};
static const int CSR_OFF[5]  = {0, 500000, 800000, 1100000, 1250000};

using bf16x8 = __attribute__((ext_vector_type(8))) short;
using u16x8  = __attribute__((ext_vector_type(8))) unsigned short;
using f32x4  = __attribute__((ext_vector_type(4))) float;

__device__ __forceinline__ float bf2f(unsigned short u) {
  return __uint_as_float(((unsigned)u) << 16);
}
__device__ __forceinline__ unsigned short f2bf(float f) {  // RNE
  unsigned u = __float_as_uint(f);
  u += 0x7FFFu + ((u >> 16) & 1u);
  return (unsigned short)(u >> 16);
}

// ---------------- k_hist: LDS histograms (din rank + dout counts) ----------------

struct HArgs { const int* esrc[5]; const int* edst[5]; int* pos; int* partial; };

__global__ __launch_bounds__(512) void k_hist(HArgs a) {
  __shared__ int hbin[8192];
  int bx = blockIdx.x;
  int t = threadIdx.x;
  if (bx < 336) {
    constexpr int DSTART[6] = {0, 112, 160, 272, 320, 336};
    constexpr int NDT[5] = {50000, 20000, 50000, 20000, 2000};
    constexpr int CS[5]  = {31250, 18750, 18750, 9375, 9375};
    constexpr int EE[5]  = {500000, 300000, 300000, 150000, 150000};
    constexpr int PB[5]  = {0, 800000, 1120000, 1920000, 2240000};
    constexpr int COFF[5] = {0, 500000, 800000, 1100000, 1250000};
    int r = 0;
    while (bx >= DSTART[r + 1]) ++r;
    int local = bx - DSTART[r];
    int g = local / 16, c = local % 16;
    int nd = NDT[r];
    int gbase = g * 8192;
    int gend = gbase + 8192 < nd ? gbase + 8192 : nd;
    const int* dst = a.edst[r];
    int* pos = a.pos + COFF[r];
    int elo = c * CS[r];
    int ehi = elo + CS[r] < EE[r] ? elo + CS[r] : EE[r];
    for (int j = t; j < 8192; j += 512) hbin[j] = 0;
    __syncthreads();
    int span = ehi - elo;
    int efull = elo + (span / 4096) * 4096;
    for (int b = elo + t; b < efull; b += 4096) {
      int d[8];
#pragma unroll
      for (int k = 0; k < 8; ++k) d[k] = dst[b + k * 512];
#pragma unroll
      for (int k = 0; k < 8; ++k)
        if (d[k] >= gbase && d[k] < gend)
          pos[b + k * 512] = atomicAdd(&hbin[d[k] - gbase], 1);
    }
    for (int e = efull + t; e < ehi; e += 512) {
      int d = dst[e];
      if (d >= gbase && d < gend) pos[e] = atomicAdd(&hbin[d - gbase], 1);
    }
    __syncthreads();
    int* out = a.partial + PB[r] + (size_t)c * nd + gbase;
    int nn = gend - gbase;
    for (int j = t; j < nn; j += 512) out[j] = hbin[j];
  } else {
    constexpr int OSTART[6] = {0, 112, 224, 272, 288, 336};
    constexpr int NST[5] = {50000, 50000, 20000, 2000, 20000};
    constexpr int CS[5]  = {31250, 18750, 18750, 9375, 9375};
    constexpr int EE[5]  = {500000, 300000, 300000, 150000, 150000};
    constexpr int PB[5]  = {2272000, 3072000, 3872000, 4192000, 4224000};
    int idx = bx - 336;
    int r = 0;
    while (idx >= OSTART[r + 1]) ++r;
    int local = idx - OSTART[r];
    int g = local / 16, c = local % 16;
    int ns = NST[r];
    int gbase = g * 8192;
    int gend = gbase + 8192 < ns ? gbase + 8192 : ns;
    const int* src = a.esrc[r];
    int elo = c * CS[r];
    int ehi = elo + CS[r] < EE[r] ? elo + CS[r] : EE[r];
    for (int j = t; j < 8192; j += 512) hbin[j] = 0;
    __syncthreads();
    int span = ehi - elo;
    int efull = elo + (span / 4096) * 4096;
    for (int b = elo + t; b < efull; b += 4096) {
      int s[8];
#pragma unroll
      for (int k = 0; k < 8; ++k) s[k] = src[b + k * 512];
#pragma unroll
      for (int k = 0; k < 8; ++k)
        if (s[k] >= gbase && s[k] < gend) atomicAdd(&hbin[s[k] - gbase], 1);
    }
    for (int e = efull + t; e < ehi; e += 512) {
      int s = src[e];
      if (s >= gbase && s < gend) atomicAdd(&hbin[s - gbase], 1);
    }
    __syncthreads();
    int* out = a.partial + PB[r] + (size_t)c * ns + gbase;
    int nn = gend - gbase;
    for (int j = t; j < nn; j += 512) out[j] = hbin[j];
  }
}

// ---------------- phase B: chunk-prefix (din, in-place) + rs + cnt ----------------

struct BArgs { int* partial; int* cnt; float* rs; };

__global__ __launch_bounds__(256) void k_scanB(BArgs a) {
  int bx = blockIdx.x;
  int t = threadIdx.x;
  if (bx < 555) {
    int i = bx * 256 + t;
    if (i >= 142000) return;
    constexpr int NDT[5] = {50000, 20000, 50000, 20000, 2000};
    constexpr int PB[5]  = {0, 800000, 1120000, 1920000, 2240000};
    constexpr int DOFF[5] = {50000, 150000, 190000, 242000, 282000};
    int r, d;
    if      (i < 50000)  { r = 0; d = i; }
    else if (i < 70000)  { r = 1; d = i - 50000; }
    else if (i < 120000) { r = 2; d = i - 70000; }
    else if (i < 140000) { r = 3; d = i - 120000; }
    else                 { r = 4; d = i - 140000; }
    int nd = NDT[r];
    int* p = a.partial + PB[r] + d;
    int run = 0;
#pragma unroll
    for (int c = 0; c < 16; ++c) {
      int v = p[(size_t)c * nd];
      p[(size_t)c * nd] = run;
      run += v;
    }
    a.cnt[DOFF[r] + d] = run;
    a.rs[DOFF[r] + d] = rsqrtf((float)(run > 1 ? run : 1));
  } else {
    int i = (bx - 555) * 256 + t;
    if (i >= 142000) return;
    constexpr int NST[5] = {50000, 50000, 20000, 2000, 20000};
    constexpr int PB[5]  = {2272000, 3072000, 3872000, 4192000, 4224000};
    constexpr int OOFF[5] = {0, 100000, 170000, 240000, 262000};
    int r, s;
    if      (i < 50000)  { r = 0; s = i; }
    else if (i < 100000) { r = 1; s = i - 50000; }
    else if (i < 120000) { r = 2; s = i - 100000; }
    else if (i < 122000) { r = 3; s = i - 120000; }
    else                 { r = 4; s = i - 122000; }
    int ns = NST[r];
    const int* p = a.partial + PB[r] + s;
    int sum = 0;
#pragma unroll
    for (int c = 0; c < 16; ++c) sum += p[(size_t)c * ns];
    a.rs[OOFF[r] + s] = rsqrtf((float)(sum > 1 ? sum : 1));
  }
}

// ---------------- scan3: rp from cnt ----------------

struct S3Args { const int* cnt; int* rp; };

__global__ __launch_bounds__(256) void k_scan3(S3Args a) {
  constexpr int CSTART[6] = {0, 49, 69, 118, 138, 140};
  constexpr int NDT[5] = {50000, 20000, 50000, 20000, 2000};
  constexpr int DOFF[5] = {50000, 150000, 190000, 242000, 282000};
  constexpr int RPOFF[5] = {0, 50001, 70002, 120003, 140004};
  int bx = blockIdx.x, r = 0;
  while (bx >= CSTART[r + 1]) ++r;
  int chunk = bx - CSTART[r];
  int nch = CSTART[r + 1] - CSTART[r];
  int n = NDT[r];
  const int* cnt = a.cnt + DOFF[r];
  int* rp = a.rp + RPOFF[r];
  int t = threadIdx.x;
  __shared__ int sd[256];
  __shared__ int choff_sh;
  int lim = chunk * 1024;
  int pre = 0;
  for (int j = t; j < lim; j += 256) pre += cnt[j];
  sd[t] = pre;
  __syncthreads();
  for (int off = 128; off > 0; off >>= 1) {
    if (t < off) sd[t] += sd[t + off];
    __syncthreads();
  }
  if (t == 0) choff_sh = sd[0];
  __syncthreads();
  int idx0 = lim + t * 4;
  int v[4];
#pragma unroll
  for (int j = 0; j < 4; ++j) v[j] = (idx0 + j < n) ? cnt[idx0 + j] : 0;
  int tsum = v[0] + v[1] + v[2] + v[3];
  sd[t] = tsum;
  __syncthreads();
  for (int s = 1; s < 256; s <<= 1) {
    int add = (t >= s) ? sd[t - s] : 0;
    __syncthreads();
    sd[t] += add;
    __syncthreads();
  }
  int off = choff_sh + sd[t] - tsum;
#pragma unroll
  for (int j = 0; j < 4; ++j) {
    if (idx0 + j < n) rp[idx0 + j] = off;
    off += v[j];
  }
  if (chunk == nch - 1 && t == 255) rp[n] = choff_sh + sd[255];
}

// ---------------- k_buildCx: CSR scatter (x4) + transform(L1) + wprep, striped 1:2 ----------------

struct TJob { const float* X; const float* W; unsigned short* Y; int M; };
struct PrepJob { const float* W0; const float* W128; unsigned short* hi;
                 unsigned short* lo; int NOUT; int lgK; int bstart; };
struct CXArgs { const int* esrc[5]; const int* edst[5]; const int* pos;
                const int* rp; const int* partial; int* csr;
                TJob tj[5]; PrepJob pj[6]; };

__device__ __forceinline__ void transform_body(const TJob& p, int bxl, int t) {
  int w = t >> 6, l = t & 63;
  int lo16 = l & 15, hi4 = l >> 4;
  int m0 = bxl * 64;
  int M = p.M;
  f32x4 acc[4][2] = {};
  for (int s = 0; s < 4; ++s) {  // K = 128, 32 per step
    int kbase = s * 32 + hi4 * 8;
    bf16x8 af[4];
#pragma unroll
    for (int mf = 0; mf < 4; ++mf) {
      int row = m0 + mf * 16 + lo16;
      row = row < M ? row : M - 1;  // clamp; OOB rows never stored
      const float* xr = &p.X[(size_t)row * 128 + kbase];
      float4 xa = *(const float4*)xr;
      float4 xb = *(const float4*)(xr + 4);
      af[mf][0] = (short)f2bf(xa.x); af[mf][1] = (short)f2bf(xa.y);
      af[mf][2] = (short)f2bf(xa.z); af[mf][3] = (short)f2bf(xa.w);
      af[mf][4] = (short)f2bf(xb.x); af[mf][5] = (short)f2bf(xb.y);
      af[mf][6] = (short)f2bf(xb.z); af[mf][7] = (short)f2bf(xb.w);
    }
#pragma unroll
    for (int nf = 0; nf < 2; ++nf) {
      int n = (w * 2 + nf) * 16 + lo16;
      bf16x8 bh, bl;
#pragma unroll
      for (int j = 0; j < 8; ++j) {
        float wv = p.W[(size_t)(kbase + j) * 128 + n];
        unsigned short h = f2bf(wv);
        bh[j] = (short)h;
        bl[j] = (short)f2bf(wv - bf2f(h));
      }
#pragma unroll
      for (int mf = 0; mf < 4; ++mf) {
        acc[mf][nf] = __builtin_amdgcn_mfma_f32_16x16x32_bf16(af[mf], bh, acc[mf][nf], 0, 0, 0);
        acc[mf][nf] = __builtin_amdgcn_mfma_f32_16x16x32_bf16(af[mf], bl, acc[mf][nf], 0, 0, 0);
      }
    }
  }
#pragma unroll
  for (int nf = 0; nf < 2; ++nf) {
    int col = (w * 2 + nf) * 16 + lo16;
#pragma unroll
    for (int mf = 0; mf < 4; ++mf) {
#pragma unroll
      for (int rr = 0; rr < 4; ++rr) {
        int row = m0 + mf * 16 + hi4 * 4 + rr;
        if (row < M) p.Y[(size_t)row * 128 + col] = f2bf(acc[mf][nf][rr]);
      }
    }
  }
}

__global__ __launch_bounds__(256) void k_buildCx(CXArgs a) {
  int bx = blockIdx.x;
  int t = threadIdx.x;
  int g = bx / 3, m = bx % 3;
  if (m == 0) {
    // CSR scatter, 1024 edges/block, 4/thread unrolled
    constexpr int ESTART[6] = {0, 489, 782, 1075, 1222, 1369};
    constexpr int NDT[5] = {50000, 20000, 50000, 20000, 2000};
    constexpr int CS[5]  = {31250, 18750, 18750, 9375, 9375};
    constexpr int EE[5]  = {500000, 300000, 300000, 150000, 150000};
    constexpr int PB[5]  = {0, 800000, 1120000, 1920000, 2240000};
    constexpr int RPOFF[5] = {0, 50001, 70002, 120003, 140004};
    constexpr int COFF[5] = {0, 500000, 800000, 1100000, 1250000};
    int idx = g;
    if (idx >= 1369) return;
    int r = 0;
    while (idx >= ESTART[r + 1]) ++r;
    int i0 = (idx - ESTART[r]) * 1024 + t;
    const int* edst = a.edst[r];
    const int* esrc = a.esrc[r];
    const int* pos = a.pos + COFF[r];
    const int* rp = a.rp + RPOFF[r];
    const int* pb = a.partial + PB[r];
    int* csr = a.csr + COFF[r];
    int E = EE[r], cs = CS[r], nd = NDT[r];
    int i[4], d[4];
    bool v[4];
#pragma unroll
    for (int k = 0; k < 4; ++k) {
      i[k] = i0 + k * 256;
      v[k] = i[k] < E;
      d[k] = v[k] ? edst[i[k]] : 0;
    }
    int slot[4];
#pragma unroll
    for (int k = 0; k < 4; ++k) {
      if (v[k]) {
        int c = i[k] / cs;
        slot[k] = rp[d[k]] + pb[(size_t)c * nd + d[k]] + pos[i[k]];
      }
    }
#pragma unroll
    for (int k = 0; k < 4; ++k)
      if (v[k]) csr[slot[k]] = esrc[i[k]];
  } else {
    int idx = g * 2 + (m - 1);
    if (idx < 2222) {
      constexpr int TSTART[6] = {0, 782, 1564, 1877, 1909, 2222};
      int r = 0;
      while (idx >= TSTART[r + 1]) ++r;
      transform_body(a.tj[r], idx - TSTART[r], t);
    } else if (idx < 2638) {
      int b = idx - 2222, ji = 0;
      while (ji < 5 && b >= a.pj[ji + 1].bstart) ++ji;
      PrepJob p = a.pj[ji];
      int eidx = (b - p.bstart) * 256 + t;
      int K = 1 << p.lgK;
      int n = eidx >> p.lgK, k = eidx & (K - 1);
      if (n >= p.NOUT) return;
      float w = (k < 128) ? p.W0[k * p.NOUT + n] : p.W128[(k - 128) * p.NOUT + n];
      unsigned short h = f2bf(w);
      float res = w - bf2f(h);
      p.hi[n * K + k] = h;
      p.lo[n * K + k] = f2bf(res);
    }
  }
}

// ---------------- shared gather inner loop ----------------
// UNCONDITIONAL 16-deep batches with masked coefficients: inactive lanes
// clamp their edge index to base+0 (valid row, L1-hit duplicate) and carry
// sc = 0.0f, so j >= m contributes exact zero. One latency wait per batch
// instead of 2-3 for the common degree ~10 case.

#define GROW(vv, cc)                                                              \
  _Pragma("unroll") for (int q = 0; q < 8; ++q)                                   \
      acc[q] = fmaf(__uint_as_float(((unsigned)(unsigned short)vv[q]) << 16), cc, acc[q]);

__device__ __forceinline__ void gat_accum(const int* __restrict__ rp,
    const int* __restrict__ csr, const unsigned short* __restrict__ Y,
    const float* __restrict__ rso, int wid, int sub, float* acc) {
  int e0 = rp[wid], e1 = rp[wid + 1];
  for (int base = e0; base < e1; base += 16) {
    int m = e1 - base;
    if (m > 16) m = 16;
    int ei = base + (sub < m ? sub : 0);
    int se = csr[ei];
    float sc = (sub < m) ? rso[se] : 0.f;
    bf16x8 v[16];
#pragma unroll
    for (int j = 0; j < 16; ++j) {
      int sj = __shfl(se, j, 16);
      v[j] = *(const bf16x8*)&Y[(size_t)sj * 128 + sub * 8];
    }
#pragma unroll
    for (int j = 0; j < 16; ++j) {
      float cj = __shfl(sc, j, 16);
      GROW(v[j], cj)
    }
  }
}

// ---------------- layer-1 gather: Y -> h1 bf16 (bias + mean + lrelu fused) ----------------

struct G1Rel { const int* rp; const int* csr; const unsigned short* Y;
               const float* rso; const float* rsi; };
struct G1Args { G1Rel rel[5]; const float* b;
                unsigned short* hU; unsigned short* hN; unsigned short* hS; };

__global__ __launch_bounds__(256) void k_gather1(G1Args a) {
  int bx = blockIdx.x;
  int t = threadIdx.x;
  int sub = t & 15;
  float acc[8], tot[8];
#pragma unroll
  for (int q = 0; q < 8; ++q) acc[q] = 0.f;
  if (bx < 3125) {  // users: rel 0 + rel 2
    int wid = bx * 16 + (t >> 4);
    gat_accum(a.rel[0].rp, a.rel[0].csr, a.rel[0].Y, a.rel[0].rso, wid, sub, acc);
    float s0 = a.rel[0].rsi[wid];
#pragma unroll
    for (int q = 0; q < 8; ++q) { tot[q] = s0 * acc[q]; acc[q] = 0.f; }
    gat_accum(a.rel[2].rp, a.rel[2].csr, a.rel[2].Y, a.rel[2].rso, wid, sub, acc);
    float s2 = a.rel[2].rsi[wid];
    const float* b0 = a.b;
    const float* b2 = a.b + 2 * 128;
    u16x8 o;
#pragma unroll
    for (int q = 0; q < 8; ++q) {
      float v = 0.5f * (tot[q] + s2 * acc[q] + b0[sub * 8 + q] + b2[sub * 8 + q]);
      v = v >= 0.f ? v : LRELU * v;
      o[q] = f2bf(v);
    }
    *(u16x8*)&a.hU[(size_t)wid * 128 + sub * 8] = o;
  } else if (bx < 4375) {  // news: rel 1 + rel 3
    int wid = (bx - 3125) * 16 + (t >> 4);
    gat_accum(a.rel[1].rp, a.rel[1].csr, a.rel[1].Y, a.rel[1].rso, wid, sub, acc);
    float s1 = a.rel[1].rsi[wid];
#pragma unroll
    for (int q = 0; q < 8; ++q) { tot[q] = s1 * acc[q]; acc[q] = 0.f; }
    gat_accum(a.rel[3].rp, a.rel[3].csr, a.rel[3].Y, a.rel[3].rso, wid, sub, acc);
    float s3 = a.rel[3].rsi[wid];
    const float* b1v = a.b + 128;
    const float* b3 = a.b + 3 * 128;
    u16x8 o;
#pragma unroll
    for (int q = 0; q < 8; ++q) {
      float v = 0.5f * (tot[q] + s3 * acc[q] + b1v[sub * 8 + q] + b3[sub * 8 + q]);
      v = v >= 0.f ? v : LRELU * v;
      o[q] = f2bf(v);
    }
    *(u16x8*)&a.hN[(size_t)wid * 128 + sub * 8] = o;
  } else {  // sources: rel 4
    int wid = (bx - 4375) * 16 + (t >> 4);
    gat_accum(a.rel[4].rp, a.rel[4].csr, a.rel[4].Y, a.rel[4].rso, wid, sub, acc);
    float s4 = a.rel[4].rsi[wid];
    const float* b4 = a.b + 4 * 128;
    u16x8 o;
#pragma unroll
    for (int q = 0; q < 8; ++q) {
      float v = s4 * acc[q] + b4[sub * 8 + q];
      v = v >= 0.f ? v : LRELU * v;
      o[q] = f2bf(v);
    }
    *(u16x8*)&a.hS[(size_t)wid * 128 + sub * 8] = o;
  }
}

// ---------------- k_gmm: fused layer-2 gather (swizzled LDS) + MFMA GEMM ----------------
// 512 threads, 64 rows/block (32KB LDS). 8 waves each compute 64 rows x 16
// cols. h2 f32 -> d_out, h2 bf16 -> h2b (not xb*: other blocks still read
// xb* as h1).

struct GMJob {
  const int* rpA; const int* csrA; const unsigned short* YA;
  const float* rsoA; const float* rsiA;
  const int* rpB; const int* csrB; const unsigned short* YB;
  const float* rsoB; const float* rsiB;
  const unsigned short* Wh; const unsigned short* Wl;
  const float* b0; const float* b1; float scale;
  float* H; unsigned short* Hb; int M; int KP;
};
struct GMArgs { GMJob j[3]; };

__global__ __launch_bounds__(512) void k_gmm(GMArgs a) {
  __shared__ unsigned short As[64 * 256];
  int bx = blockIdx.x;
  int ji, bxl;
  if (bx < 782)       { ji = 0; bxl = bx; }
  else if (bx < 1095) { ji = 1; bxl = bx - 782; }
  else                { ji = 2; bxl = bx - 1095; }
  const GMJob& p = a.j[ji];
  int t = threadIdx.x;
  int m0 = bxl * 64;
  char* asb = (char*)As;
  // ---- gather phase: 32 rows per pass (512/16), 2 passes ----
  int sub = t & 15;
  int rowloc = t >> 4;  // 0..31
  for (int half = 0; half < 2; ++half) {
    int rl = rowloc + half * 32;
    int wid = m0 + rl;
    bool ok = wid < p.M;
    {
      float acc[8];
#pragma unroll
      for (int q = 0; q < 8; ++q) acc[q] = 0.f;
      float si = 0.f;
      if (ok) { gat_accum(p.rpA, p.csrA, p.YA, p.rsoA, wid, sub, acc); si = p.rsiA[wid]; }
      u16x8 o;
#pragma unroll
      for (int q = 0; q < 8; ++q) o[q] = f2bf(acc[q] * si);
      int cb = sub * 16;
      *(u16x8*)(asb + rl * 512 + (cb ^ ((rl & 7) << 4))) = o;
    }
    if (p.rpB) {
      float acc[8];
#pragma unroll
      for (int q = 0; q < 8; ++q) acc[q] = 0.f;
      float si = 0.f;
      if (ok) { gat_accum(p.rpB, p.csrB, p.YB, p.rsoB, wid, sub, acc); si = p.rsiB[wid]; }
      u16x8 o;
#pragma unroll
      for (int q = 0; q < 8; ++q) o[q] = f2bf(acc[q] * si);
      int cb = 256 + sub * 16;
      *(u16x8*)(asb + rl * 512 + (cb ^ ((rl & 7) << 4))) = o;
    }
  }
  __syncthreads();
  // ---- GEMM phase: 8 waves, each 64 rows x 16 cols ----
  int w = t >> 6, l = t & 63;
  int lo16 = l & 15, hi4 = l >> 4;
  int KP = p.KP;
  f32x4 acc[4] = {};
  for (int s = 0; s < KP / 32; ++s) {
    int kbase = s * 32 + hi4 * 8;
    int cb = kbase * 2;
    bf16x8 af[4];
#pragma unroll
    for (int mf = 0; mf < 4; ++mf) {
      int row = mf * 16 + lo16;
      af[mf] = *(const bf16x8*)(asb + row * 512 + (cb ^ ((row & 7) << 4)));
    }
    int n = w * 16 + lo16;
    bf16x8 bh = *(const bf16x8*)&p.Wh[(size_t)n * KP + kbase];
    bf16x8 bl = *(const bf16x8*)&p.Wl[(size_t)n * KP + kbase];
#pragma unroll
    for (int mf = 0; mf < 4; ++mf) {
      acc[mf] = __builtin_amdgcn_mfma_f32_16x16x32_bf16(af[mf], bh, acc[mf], 0, 0, 0);
      acc[mf] = __builtin_amdgcn_mfma_f32_16x16x32_bf16(af[mf], bl, acc[mf], 0, 0, 0);
    }
  }
  int col = w * 16 + lo16;
  float bs = p.b0[col];
  if (p.b1) bs += p.b1[col];
#pragma unroll
  for (int mf = 0; mf < 4; ++mf) {
#pragma unroll
    for (int rr = 0; rr < 4; ++rr) {
      int row = m0 + mf * 16 + hi4 * 4 + rr;
      if (row < p.M) {
        float o = p.scale * (acc[mf][rr] + bs);
        o = o >= 0.f ? o : LRELU * o;
        p.H[(size_t)row * 128 + col] = o;
        p.Hb[(size_t)row * 128 + col] = f2bf(o);
      }
    }
  }
}

// ---------------- projection GEMM (3 dst-types, one launch) ----------------

struct MJob { const unsigned short* A; const unsigned short* Wh; const unsigned short* Wl;
              const float* b0; const float* b1; float scale; int lrelu;
              float* H; int ldh; unsigned short* Hb; int M; int bstart; };
struct MArgs { MJob j[3]; };

template <int KCH, int NW>
__device__ __forceinline__ void mgemm_body(const MJob& p, int bxl) {
  constexpr int KP = KCH * 128;
  int t = threadIdx.x;
  int w = t >> 6, l = t & 63;
  int lo16 = l & 15, hi4 = l >> 4;
  int m0 = bxl * 64;
  int M = p.M;
  const unsigned short* A = p.A;
  f32x4 acc[4][NW] = {};
  for (int s = 0; s < KP / 32; ++s) {
    int kbase = s * 32 + hi4 * 8;
    bf16x8 af[4];
#pragma unroll
    for (int mf = 0; mf < 4; ++mf) {
      int row = m0 + mf * 16 + lo16;
      row = row < M ? row : M - 1;  // clamp; OOB rows never stored
      af[mf] = *(const bf16x8*)&A[(size_t)row * KP + kbase];
    }
#pragma unroll
    for (int nf = 0; nf < NW; ++nf) {
      int n = (w * NW + nf) * 16 + lo16;
      bf16x8 bh = *(const bf16x8*)&p.Wh[(size_t)n * KP + kbase];
      bf16x8 bl = *(const bf16x8*)&p.Wl[(size_t)n * KP + kbase];
#pragma unroll
      for (int mf = 0; mf < 4; ++mf) {
        acc[mf][nf] = __builtin_amdgcn_mfma_f32_16x16x32_bf16(af[mf], bh, acc[mf][nf], 0, 0, 0);
        acc[mf][nf] = __builtin_amdgcn_mfma_f32_16x16x32_bf16(af[mf], bl, acc[mf][nf], 0, 0, 0);
      }
    }
  }
#pragma unroll
  for (int nf = 0; nf < NW; ++nf) {
    int col = (w * NW + nf) * 16 + lo16;
    float bs = p.b0 ? p.b0[col] : 0.f;
    if (p.b1) bs += p.b1[col];
#pragma unroll
    for (int mf = 0; mf < 4; ++mf) {
#pragma unroll
      for (int rr = 0; rr < 4; ++rr) {
        int row = m0 + mf * 16 + hi4 * 4 + rr;
        if (row < M) {
          float o = p.scale * (acc[mf][nf][rr] + bs);
          if (p.lrelu) o = o >= 0.f ? o : LRELU * o;
          if (p.H) p.H[(size_t)row * p.ldh + col] = o;
          if (p.Hb) p.Hb[(size_t)row * p.ldh + col] = f2bf(o);
        }
      }
    }
  }
}

__global__ __launch_bounds__(256) void k_proj3(MArgs a) {
  int bx = blockIdx.x;
  if (bx < a.j[1].bstart)      mgemm_body<1, 1>(a.j[0], bx);
  else if (bx < a.j[2].bstart) mgemm_body<1, 1>(a.j[1], bx - a.j[1].bstart);
  else                         mgemm_body<1, 1>(a.j[2], bx - a.j[2].bstart);
}

// ---------------- host ----------------

extern "C" void kernel_launch(void* const* d_in, const int* in_sizes, int n_in,
                              void* d_out, int out_size, void* d_ws, size_t ws_size,
                              hipStream_t stream) {
  const float* xu = (const float*)d_in[0];
  const float* xn = (const float*)d_in[1];
  const float* xs = (const float*)d_in[2];
  const float* W1 = (const float*)d_in[3];
  const float* b1 = (const float*)d_in[4];
  const float* W2 = (const float*)d_in[5];
  const float* b2 = (const float*)d_in[6];
  const float* Wu = (const float*)d_in[7];
  const float* bu = (const float*)d_in[8];
  const float* Wn = (const float*)d_in[9];
  const float* bn = (const float*)d_in[10];
  const float* Wsrc = (const float*)d_in[11];
  const float* bsrc = (const float*)d_in[12];
  const int* SRC[5] = {(const int*)d_in[13], (const int*)d_in[15], (const int*)d_in[17],
                       (const int*)d_in[19], (const int*)d_in[21]};
  const int* DST[5] = {(const int*)d_in[14], (const int*)d_in[16], (const int*)d_in[18],
                       (const int*)d_in[20], (const int*)d_in[22]};

  // ---- workspace layout ----
  int* ws_i = (int*)d_ws;
  int* rp = ws_i;                           // 142008
  int* csr = ws_i + 142008;                 // 1400000
  int* pos = ws_i + 1542008;                // 1400000
  int* cnt = ws_i + 2942328;                // 284000 (din slots used)
  float* rs = (float*)(ws_i + 3226328);     // 284000
  unsigned short* wt = (unsigned short*)(rs + 284000);    // 376832
  unsigned short* h2bU = wt + 376832;       // 50000*128 (h2 bf16)
  unsigned short* h2bN = h2bU + 6400000;    // 20000*128
  unsigned short* h2bS = h2bN + 2560000;    // 2000*128
  unsigned short* xbU = wt + 376832 + 18176000; // 50000*128 (h1 bf16)
  unsigned short* xbN = xbU + 6400000;      // 20000*128
  unsigned short* xbS = xbN + 2560000;      // 2000*128

  // wt sub-offsets (hi, lo consecutive)
  unsigned short* L2U_h = wt + 163840, * L2U_l = wt + 196608;
  unsigned short* L2N_h = wt + 229376, * L2N_l = wt + 262144;
  unsigned short* L2S_h = wt + 294912, * L2S_l = wt + 311296;
  unsigned short* PU_h = wt + 327680, * PU_l = wt + 335872;
  unsigned short* PN_h = wt + 344064, * PN_l = wt + 352256;
  unsigned short* PS_h = wt + 360448, * PS_l = wt + 368640;

  // ---- d_out layout ----
  float* outf = (float*)d_out;
  float* ou = outf;                 // 50000*64
  float* on = outf + 3200000;       // 20000*64
  float* osrc = outf + 4480000;     // 2000*64
  float* hu = outf + 4608000;       // 50000*128
  float* hn = outf + 11008000;      // 20000*128
  float* hs = outf + 13568000;      // 2000*128

  // histogram partials / chunk-bases: 4.544M ints in ou+on+osrc region,
  // dead until k_proj3; consumed by scanB/scan3/buildCx.
  int* partial = (int*)outf;

  // layer-1 transform outputs Y_r (bf16) in hu/hn/hs region; consumed by
  // k_gather1, dead before k_gmm overwrites hu/hn/hs with h2 f32.
  unsigned short* Yb = (unsigned short*)(outf + 4608000);
  unsigned short* Y0 = Yb;              // 50000*128 (follows, src U)
  unsigned short* Y1 = Y0 + 6400000;    // 50000*128 (posts, src U)
  unsigned short* Y2a = Y1 + 6400000;   // 20000*128 (posted_by, src N)
  unsigned short* Y3 = Y2a + 2560000;   // 2000*128  (publishes, src S)
  unsigned short* Y4 = Y3 + 256000;     // 20000*128 (published_by, src N)

  // ---- k_hist: din rank-hist + dout hist (512t, unroll-8) ----
  HArgs ha;
  for (int r = 0; r < 5; ++r) { ha.esrc[r] = SRC[r]; ha.edst[r] = DST[r]; }
  ha.pos = pos;
  ha.partial = partial;
  k_hist<<<672, 512, 0, stream>>>(ha);

  // ---- phase B: chunk prefixes + rs + cnt ----
  BArgs ba = {partial, cnt, rs};
  k_scanB<<<1110, 256, 0, stream>>>(ba);

  // ---- rp scan ----
  S3Args s3 = {cnt, rp};
  k_scan3<<<140, 256, 0, stream>>>(s3);

  // ---- buildC (x4 unrolled) + transform(L1) + wprep, striped 1:2 ----
  CXArgs ca;
  for (int r = 0; r < 5; ++r) { ca.esrc[r] = SRC[r]; ca.edst[r] = DST[r]; }
  ca.pos = pos;
  ca.rp = rp;
  ca.partial = partial;
  ca.csr = csr;
  ca.tj[0] = {xu, W1 + 0 * 16384, Y0, kNU};
  ca.tj[1] = {xu, W1 + 1 * 16384, Y1, kNU};
  ca.tj[2] = {xn, W1 + 2 * 16384, Y2a, kNN};
  ca.tj[3] = {xs, W1 + 3 * 16384, Y3, kNS};
  ca.tj[4] = {xn, W1 + 4 * 16384, Y4, kNN};
  ca.pj[0] = {W2, W2 + 2 * 16384, L2U_h, L2U_l, 128, 8, 0};
  ca.pj[1] = {W2 + 16384, W2 + 3 * 16384, L2N_h, L2N_l, 128, 8, 128};
  ca.pj[2] = {W2 + 4 * 16384, nullptr, L2S_h, L2S_l, 128, 7, 256};
  ca.pj[3] = {Wu, nullptr, PU_h, PU_l, 64, 7, 320};
  ca.pj[4] = {Wn, nullptr, PN_h, PN_l, 64, 7, 352};
  ca.pj[5] = {Wsrc, nullptr, PS_h, PS_l, 64, 7, 384};
  k_buildCx<<<4107, 256, 0, stream>>>(ca);

  // ---- layer 1: gather Y -> h1 (bf16 into xb*) ----
  G1Args g1;
  const unsigned short* YT[5] = {Y0, Y1, Y2a, Y3, Y4};
  for (int r = 0; r < 5; ++r)
    g1.rel[r] = {rp + RP_OFF[r], csr + CSR_OFF[r], YT[r],
                 rs + DOUT_OFF[r], rs + DIN_OFF[r]};
  g1.b = b1;
  g1.hU = xbU; g1.hN = xbN; g1.hS = xbS;
  k_gather1<<<4500, 256, 0, stream>>>(g1);

  // ---- layer 2: fused gather+GEMM -> h2 (f32 into d_out, bf16 into h2b*) ----
  GMArgs gm;
  gm.j[0] = {rp + RP_OFF[0], csr + CSR_OFF[0], xbU, rs + DOUT_OFF[0], rs + DIN_OFF[0],
             rp + RP_OFF[2], csr + CSR_OFF[2], xbN, rs + DOUT_OFF[2], rs + DIN_OFF[2],
             L2U_h, L2U_l, b2, b2 + 2 * 128, 0.5f, hu, h2bU, kNU, 256};
  gm.j[1] = {rp + RP_OFF[1], csr + CSR_OFF[1], xbU, rs + DOUT_OFF[1], rs + DIN_OFF[1],
             rp + RP_OFF[3], csr + CSR_OFF[3], xbS, rs + DOUT_OFF[3], rs + DIN_OFF[3],
             L2N_h, L2N_l, b2 + 128, b2 + 3 * 128, 0.5f, hn, h2bN, kNN, 256};
  gm.j[2] = {rp + RP_OFF[4], csr + CSR_OFF[4], xbN, rs + DOUT_OFF[4], rs + DIN_OFF[4],
             nullptr, nullptr, nullptr, nullptr, nullptr,
             L2S_h, L2S_l, b2 + 4 * 128, nullptr, 1.0f, hs, h2bS, kNS, 128};
  k_gmm<<<1127, 512, 0, stream>>>(gm);

  // ---- output projections (read bf16 h2 from h2b*) ----
  MArgs pm;
  pm.j[0] = {h2bU, PU_h, PU_l, bu, nullptr, 1.0f, 0, ou, 64, nullptr, kNU, 0};
  pm.j[1] = {h2bN, PN_h, PN_l, bn, nullptr, 1.0f, 0, on, 64, nullptr, kNN, 782};
  pm.j[2] = {h2bS, PS_h, PS_l, bsrc, nullptr, 1.0f, 0, osrc, 64, nullptr, kNS, 1095};
  k_proj3<<<1127, 256, 0, stream>>>(pm);
}